// Round 1
// baseline (3510.541 us; speedup 1.0000x reference)
//
#include <hip/hip_runtime.h>
#include <stdint.h>

typedef unsigned short u16;
typedef __bf16 bf16x8 __attribute__((ext_vector_type(8)));
typedef float  f32x4  __attribute__((ext_vector_type(4)));

// Dropout mask bit-generation flavor (JAX threefry):
//  1: partitionable (default since jax 0.4.36): ctr=(0,i), bits = o0^o1
//  0: legacy iota-split: i<half -> o0 of (i, i+half); else o1 of (i-half, i)
//  2: partitionable with swapped counter words: ctr=(i,0), bits = o0^o1
#define MASK_MODE 1

static __device__ __forceinline__ u16 f2bf(float f) {
  uint32_t u = __builtin_bit_cast(uint32_t, f);
  u += 0x7fffu + ((u >> 16) & 1u);            // RNE
  return (u16)(u >> 16);
}
static __device__ __forceinline__ uint32_t pack2(float a, float b) {
  return (uint32_t)f2bf(a) | ((uint32_t)f2bf(b) << 16);
}

static __device__ __forceinline__ void tf2x32(uint32_t k0, uint32_t k1,
                                              uint32_t& x0, uint32_t& x1) {
  const uint32_t ks2 = k0 ^ k1 ^ 0x1BD11BDAu;
#define TFR(r) { x0 += x1; x1 = (x1 << (r)) | (x1 >> (32 - (r))); x1 ^= x0; }
  x0 += k0; x1 += k1;
  TFR(13) TFR(15) TFR(26) TFR(6)
  x0 += k1;  x1 += ks2 + 1u;
  TFR(17) TFR(29) TFR(16) TFR(24)
  x0 += ks2; x1 += k0 + 2u;
  TFR(13) TFR(15) TFR(26) TFR(6)
  x0 += k0;  x1 += k1 + 3u;
  TFR(17) TFR(29) TFR(16) TFR(24)
  x0 += k1;  x1 += ks2 + 4u;
  TFR(13) TFR(15) TFR(26) TFR(6)
  x0 += ks2; x1 += k0 + 5u;
#undef TFR
}

// keep iff uniform(bits) < 0.5  <=>  MSB(bits) == 0
static __device__ __forceinline__ bool keep_mask(uint32_t seed, uint32_t idx) {
#if MASK_MODE == 1
  uint32_t x0 = 0u, x1 = idx;
  tf2x32(0u, seed, x0, x1);
  return ((x0 ^ x1) & 0x80000000u) == 0u;
#elif MASK_MODE == 0
  const uint32_t half = (16384u * 128u) / 2u;
  uint32_t a = (idx < half) ? idx : (idx - half);
  uint32_t b = (idx < half) ? (idx + half) : idx;
  tf2x32(0u, seed, a, b);
  uint32_t bits = (idx < half) ? a : b;
  return (bits & 0x80000000u) == 0u;
#else
  uint32_t x0 = idx, x1 = 0u;
  tf2x32(0u, seed, x0, x1);
  return ((x0 ^ x1) & 0x80000000u) == 0u;
#endif
}

// ---------------------------------------------------------------------------
// prep_w: W1(512x128), W2(128x128), W3(128x128) fp32 -> bf16 transposed
// Wt layout (u16 elements): Wt1[128][512] @0, Wt2[128][128] @65536, Wt3 @81920
__global__ __launch_bounds__(256) void prep_w(const float* __restrict__ W1,
                                              const float* __restrict__ W2,
                                              const float* __restrict__ W3,
                                              u16* __restrict__ Wt) {
  int t = blockIdx.x * 256 + threadIdx.x;   // 0..98303
  if (t < 65536) {
    int k = t >> 7, n = t & 127;
    Wt[(size_t)n * 512 + k] = f2bf(W1[t]);
  } else if (t < 81920) {
    int u = t - 65536; int k = u >> 7, n = u & 127;
    Wt[65536 + (size_t)n * 128 + k] = f2bf(W2[u]);
  } else {
    int u = t - 81920; int k = u >> 7, n = u & 127;
    Wt[81920 + (size_t)n * 128 + k] = f2bf(W3[u]);
  }
}

// ---------------------------------------------------------------------------
// tgemm_x: Tt[n][m] = (x @ W1)[m][n] in bf16.  M=16384, K=512, N=128.
// A = x fp32 (row stride 512), B = Wt1 bf16 [128][512]
__global__ __launch_bounds__(256) void tgemm_x(const float* __restrict__ X,
                                               const u16* __restrict__ Wt,
                                               u16* __restrict__ Tt) {
  __shared__ u16 As[32][136];
  __shared__ u16 Bs[128][136];
  const int t = threadIdx.x;
  const int r0 = blockIdx.x * 32;
  const int lane = t & 63, wv = t >> 6;
  const int ln = lane & 15, quad = lane >> 4;
  const int wr = (wv & 1) * 16, wc = (wv >> 1) * 64;
  const int ar = t >> 5, ac = (t & 31) * 4;
  const int bn = t >> 4, bc = (t & 15) * 8;

  const float* ap = X + (size_t)(r0 + ar) * 512 + ac;
  const u16*   bp = Wt + (size_t)bn * 512 + bc;

  f32x4 acc[4] = {{0,0,0,0},{0,0,0,0},{0,0,0,0},{0,0,0,0}};
  float4 pa[4];
  uint4  pb[8];
#pragma unroll
  for (int i = 0; i < 4; ++i) pa[i] = *(const float4*)(ap + (size_t)i * 8 * 512);
#pragma unroll
  for (int i = 0; i < 8; ++i) pb[i] = *(const uint4*)(bp + (size_t)i * 16 * 512);

  for (int s = 0; s < 4; ++s) {
    __syncthreads();
#pragma unroll
    for (int i = 0; i < 4; ++i) {
      uint2 v; v.x = pack2(pa[i].x, pa[i].y); v.y = pack2(pa[i].z, pa[i].w);
      *(uint2*)&As[ar + 8 * i][ac] = v;
    }
#pragma unroll
    for (int i = 0; i < 8; ++i) *(uint4*)&Bs[bn + 16 * i][bc] = pb[i];
    __syncthreads();
    if (s < 3) {
      const float* ap2 = ap + (size_t)(s + 1) * 128;
      const u16*   bp2 = bp + (size_t)(s + 1) * 128;
#pragma unroll
      for (int i = 0; i < 4; ++i) pa[i] = *(const float4*)(ap2 + (size_t)i * 8 * 512);
#pragma unroll
      for (int i = 0; i < 8; ++i) pb[i] = *(const uint4*)(bp2 + (size_t)i * 16 * 512);
    }
#pragma unroll
    for (int kc = 0; kc < 4; ++kc) {
      bf16x8 af = *(const bf16x8*)&As[wr + ln][kc * 32 + quad * 8];
#pragma unroll
      for (int nt = 0; nt < 4; ++nt) {
        bf16x8 bfr = *(const bf16x8*)&Bs[wc + nt * 16 + ln][kc * 32 + quad * 8];
        acc[nt] = __builtin_amdgcn_mfma_f32_16x16x32_bf16(af, bfr, acc[nt], 0, 0, 0);
      }
    }
  }
  const int m0 = r0 + wr + quad * 4;
#pragma unroll
  for (int nt = 0; nt < 4; ++nt) {
    const int n = wc + nt * 16 + ln;
    uint2 v; v.x = pack2(acc[nt][0], acc[nt][1]); v.y = pack2(acc[nt][2], acc[nt][3]);
    *(uint2*)(Tt + (size_t)n * 16384 + m0) = v;
  }
}

// ---------------------------------------------------------------------------
// tgemm_d: Tt[n][m] = (Xd @ W)[m][n] in bf16.  M=16384, K=128, N=128.
// A = xdrop bf16 [16384][128], B = Wt bf16 [128][128]
__global__ __launch_bounds__(256) void tgemm_d(const u16* __restrict__ Xd,
                                               const u16* __restrict__ Wt,
                                               u16* __restrict__ Tt) {
  __shared__ u16 As[32][136];
  __shared__ u16 Bs[128][136];
  const int t = threadIdx.x;
  const int r0 = blockIdx.x * 32;
  const int lane = t & 63, wv = t >> 6;
  const int ln = lane & 15, quad = lane >> 4;
  const int wr = (wv & 1) * 16, wc = (wv >> 1) * 64;
  const int xar = t >> 4, xac = (t & 15) * 8;
  const int bn = t >> 4, bc = (t & 15) * 8;

  uint4 va0 = *(const uint4*)(Xd + (size_t)(r0 + xar) * 128 + xac);
  uint4 va1 = *(const uint4*)(Xd + (size_t)(r0 + xar + 16) * 128 + xac);
  uint4 vb[8];
#pragma unroll
  for (int i = 0; i < 8; ++i) vb[i] = *(const uint4*)(Wt + (size_t)(bn + 16 * i) * 128 + bc);

  *(uint4*)&As[xar][xac] = va0;
  *(uint4*)&As[xar + 16][xac] = va1;
#pragma unroll
  for (int i = 0; i < 8; ++i) *(uint4*)&Bs[bn + 16 * i][bc] = vb[i];
  __syncthreads();

  f32x4 acc[4] = {{0,0,0,0},{0,0,0,0},{0,0,0,0},{0,0,0,0}};
#pragma unroll
  for (int kc = 0; kc < 4; ++kc) {
    bf16x8 af = *(const bf16x8*)&As[wr + ln][kc * 32 + quad * 8];
#pragma unroll
    for (int nt = 0; nt < 4; ++nt) {
      bf16x8 bfr = *(const bf16x8*)&Bs[wc + nt * 16 + ln][kc * 32 + quad * 8];
      acc[nt] = __builtin_amdgcn_mfma_f32_16x16x32_bf16(af, bfr, acc[nt], 0, 0, 0);
    }
  }
  const int m0 = r0 + wr + quad * 4;
#pragma unroll
  for (int nt = 0; nt < 4; ++nt) {
    const int n = wc + nt * 16 + ln;
    uint2 v; v.x = pack2(acc[nt][0], acc[nt][1]); v.y = pack2(acc[nt][2], acc[nt][3]);
    *(uint2*)(Tt + (size_t)n * 16384 + m0) = v;
  }
}

// ---------------------------------------------------------------------------
// big_gemm: C[32x128 tile] = adj[M=16384,K=16384] @ T (B given as Tt[n][k] bf16)
// EP=1: relu -> out fp32, dropout(seed) -> xdrop bf16
// EP=2: out fp32, dropout(seed) -> xdrop bf16
// EP=3: out fp32 only
template <int EP>
__global__ __launch_bounds__(256) void big_gemm(const float* __restrict__ adj,
                                                const u16* __restrict__ Tt,
                                                const float* __restrict__ bias,
                                                float* __restrict__ out,
                                                u16* __restrict__ xdrop,
                                                uint32_t seed) {
  __shared__ u16 As[32][136];
  __shared__ u16 Bs[128][136];
  const int t = threadIdx.x;
  const int r0 = blockIdx.x * 32;
  const int lane = t & 63, wv = t >> 6;
  const int ln = lane & 15, quad = lane >> 4;
  const int wr = (wv & 1) * 16, wc = (wv >> 1) * 64;
  const int ar = t >> 5, ac = (t & 31) * 4;   // A: 32x128 fp32 tile
  const int bn = t >> 4, bc = (t & 15) * 8;   // B: 128x128 bf16 tile

  const float* ap = adj + (size_t)(r0 + ar) * 16384 + ac;
  const u16*   bp = Tt + (size_t)bn * 16384 + bc;

  f32x4 acc[4] = {{0,0,0,0},{0,0,0,0},{0,0,0,0},{0,0,0,0}};
  float4 pa[4];
  uint4  pb[8];
#pragma unroll
  for (int i = 0; i < 4; ++i) pa[i] = *(const float4*)(ap + (size_t)i * 8 * 16384);
#pragma unroll
  for (int i = 0; i < 8; ++i) pb[i] = *(const uint4*)(bp + (size_t)i * 16 * 16384);

  for (int s = 0; s < 128; ++s) {
    __syncthreads();
#pragma unroll
    for (int i = 0; i < 4; ++i) {
      uint2 v; v.x = pack2(pa[i].x, pa[i].y); v.y = pack2(pa[i].z, pa[i].w);
      *(uint2*)&As[ar + 8 * i][ac] = v;
    }
#pragma unroll
    for (int i = 0; i < 8; ++i) *(uint4*)&Bs[bn + 16 * i][bc] = pb[i];
    __syncthreads();
    if (s < 127) {
      const float* ap2 = ap + (size_t)(s + 1) * 128;
      const u16*   bp2 = bp + (size_t)(s + 1) * 128;
#pragma unroll
      for (int i = 0; i < 4; ++i) pa[i] = *(const float4*)(ap2 + (size_t)i * 8 * 16384);
#pragma unroll
      for (int i = 0; i < 8; ++i) pb[i] = *(const uint4*)(bp2 + (size_t)i * 16 * 16384);
    }
#pragma unroll
    for (int kc = 0; kc < 4; ++kc) {
      bf16x8 af = *(const bf16x8*)&As[wr + ln][kc * 32 + quad * 8];
#pragma unroll
      for (int nt = 0; nt < 4; ++nt) {
        bf16x8 bfr = *(const bf16x8*)&Bs[wc + nt * 16 + ln][kc * 32 + quad * 8];
        acc[nt] = __builtin_amdgcn_mfma_f32_16x16x32_bf16(af, bfr, acc[nt], 0, 0, 0);
      }
    }
  }

#pragma unroll
  for (int nt = 0; nt < 4; ++nt) {
    const int gn = wc + nt * 16 + ln;
    const float bv = bias[gn];
#pragma unroll
    for (int r = 0; r < 4; ++r) {
      const int gm = r0 + wr + quad * 4 + r;
      const uint32_t fi = (uint32_t)gm * 128u + (uint32_t)gn;
      float pre = acc[nt][r] + bv;
      if (EP == 1) {
        float v = fmaxf(pre, 0.f);
        out[fi] = v;
        bool k = keep_mask(seed, fi);
        xdrop[fi] = k ? f2bf(2.f * v) : (u16)0;
      } else if (EP == 2) {
        out[fi] = pre;
        bool k = keep_mask(seed, fi);
        xdrop[fi] = k ? f2bf(2.f * pre) : (u16)0;
      } else {
        out[fi] = pre;
      }
    }
  }
}

// ---------------------------------------------------------------------------
extern "C" void kernel_launch(void* const* d_in, const int* in_sizes, int n_in,
                              void* d_out, int out_size, void* d_ws, size_t ws_size,
                              hipStream_t stream) {
  const float* x   = (const float*)d_in[0];   // 16384 x 512
  const float* adj = (const float*)d_in[1];   // 16384 x 16384
  const float* W1  = (const float*)d_in[2];   // 512 x 128
  const float* b1  = (const float*)d_in[3];   // 128
  const float* W2  = (const float*)d_in[4];   // 128 x 128
  const float* b2  = (const float*)d_in[5];   // 128
  const float* W3  = (const float*)d_in[6];   // 128 x 128
  const float* b3  = (const float*)d_in[7];   // 128

  float* out  = (float*)d_out;                 // [x11 | x22 | x3], each 2097152 fp32
  float* out1 = out + 2097152;
  float* out2 = out + 4194304;

  // ws: Tt bf16 [128][16384] (4 MB) @0 ; Wt bf16 (192 KB) @4MB.
  // xdrop bf16 [16384][128] (4 MB) overlays the first half of the out2 region:
  // it is dead before big_gemm<3> overwrites out2.
  u16* Tt    = (u16*)d_ws;
  u16* Wt    = (u16*)((char*)d_ws + (4u << 20));
  u16* xdrop = (u16*)out2;

  prep_w<<<384, 256, 0, stream>>>(W1, W2, W3, Wt);

  tgemm_x<<<512, 256, 0, stream>>>(x, Wt, Tt);                       // T1
  big_gemm<1><<<512, 256, 0, stream>>>(adj, Tt, b1, out, xdrop, 101u);

  tgemm_d<<<512, 256, 0, stream>>>(xdrop, Wt + 65536, Tt);           // T2
  big_gemm<2><<<512, 256, 0, stream>>>(adj, Tt, b2, out1, xdrop, 202u);

  tgemm_d<<<512, 256, 0, stream>>>(xdrop, Wt + 81920, Tt);           // T3
  big_gemm<3><<<512, 256, 0, stream>>>(adj, Tt, b3, out2, nullptr, 0u);
}